// Round 2
// baseline (134.670 us; speedup 1.0000x reference)
//
#include <hip/hip_runtime.h>

#define BN 4
#define C 256
#define H 64
#define W 64
#define CM 64
#define G 16
#define GC 16
#define KS 7
#define K2 49
#define PADD 3
#define EPSV 1e-5f

// workspace layout (float offsets)
#define W1T_OFF 0                        // [256][64]  w1T[c][o]
#define W2T_OFF (W1T_OFF + C*CM)         // [64][784]  w2T[o][j]
#define S1_OFF  (W2T_OFF + CM*784)       // [64]
#define B1_OFF  (S1_OFF + CM)            // [64]
#define S2_OFF  (B1_OFF + CM)            // [256]
#define B2C_OFF (S2_OFF + C)             // [256]
#define ZERO_OFF (B2C_OFF + C)           // [16] zeros (OOB redirect target)
#define T_OFF   (ZERO_OFF + 16)          // [4][64 tiles][64 pix][64 o]

__device__ __forceinline__ void gload_lds4(const float* g, float* l) {
  __builtin_amdgcn_global_load_lds(
      (const __attribute__((address_space(1))) void*)g,
      (__attribute__((address_space(3))) void*)l, 4, 0, 0);
}

__global__ __launch_bounds__(256) void prep_kernel(
    const float* __restrict__ w1, const float* __restrict__ w2,
    const float* __restrict__ g1, const float* __restrict__ be1,
    const float* __restrict__ m1, const float* __restrict__ v1,
    const float* __restrict__ g2, const float* __restrict__ be2,
    const float* __restrict__ m2, const float* __restrict__ v2,
    float* __restrict__ ws) {
  int tid = blockIdx.x * 256 + threadIdx.x;
  int nthr = gridDim.x * 256;
  for (int i = tid; i < CM * C; i += nthr) {
    int o = i / C, c = i - o * C;
    ws[W1T_OFF + c * CM + o] = w1[i];
  }
  for (int i = tid; i < 784 * CM; i += nthr) {
    int j = i / CM, o = i - j * CM;
    ws[W2T_OFF + o * 784 + j] = w2[i];
  }
  if (tid < CM) {
    float inv = g1[tid] * rsqrtf(v1[tid] + EPSV);
    ws[S1_OFF + tid] = inv;
    ws[B1_OFF + tid] = be1[tid] - m1[tid] * inv;
  }
  if (tid < C) {
    float inv = g2[tid] * rsqrtf(v2[tid] + EPSV);
    ws[S2_OFF + tid] = inv;
    ws[B2C_OFF + tid] = be2[tid] - m2[tid] * inv;
  }
  if (tid < 16) ws[ZERO_OFF + tid] = 0.f;
}

// t = relu(bn1(w1 @ x)), layout t[b][tile][pix][o] (o fastest).
// grid (64 y, 4 b, 2 o-half); block 256 = 4 waves (c-quarter per wave).
__global__ __launch_bounds__(256) void t_kernel(
    const float* __restrict__ x, const float* __restrict__ ws,
    float* __restrict__ t) {
  __shared__ float part[4][32][64];
  int p = threadIdx.x & 63;
  int q = __builtin_amdgcn_readfirstlane(threadIdx.x >> 6);
  int y = blockIdx.x, b = blockIdx.y, oh = blockIdx.z;
  const float* __restrict__ w1T = ws + W1T_OFF + oh * 32;

  float acc[32];
#pragma unroll
  for (int o = 0; o < 32; ++o) acc[o] = 0.f;
  const float* __restrict__ xrow = x + (((size_t)b * C + q * 64) * H + y) * W;
#pragma unroll 2
  for (int cc = 0; cc < 64; ++cc) {
    float xv = xrow[(size_t)cc * H * W + p];
    const float* __restrict__ wr = w1T + (q * 64 + cc) * CM;
#pragma unroll
    for (int o = 0; o < 32; ++o) acc[o] = fmaf(wr[o], xv, acc[o]);
  }
#pragma unroll
  for (int o = 0; o < 32; ++o) part[q][o][p] = acc[o];
  __syncthreads();

  int tile = (y >> 3) * 8 + (p >> 3);
  int pix = (y & 7) * 8 + (p & 7);
  const float* __restrict__ s1 = ws + S1_OFF + oh * 32;
  const float* __restrict__ b1 = ws + B1_OFF + oh * 32;
  float4 v4[2];
#pragma unroll
  for (int i = 0; i < 8; ++i) {
    int o = q * 8 + i;
    float s = part[0][o][p] + part[1][o][p] + part[2][o][p] + part[3][o][p];
    (&v4[0].x)[i] = fmaxf(fmaf(s, s1[o], b1[o]), 0.f);
  }
  float4* dst = (float4*)(t + ((size_t)(b * 64 + tile) * 64 + pix) * 64 + oh * 32 + q * 8);
  dst[0] = v4[0];
  dst[1] = v4[1];
}

// per (b, group, 8x8 tile), one wave, no barriers:
// t tile in regs ([pix][o] layout), halo for 16 channels via global_load_lds
// (two batches of 8, counted vmcnt so latency hides under the 49x64 GEMM).
__global__ __launch_bounds__(64, 2) void inv_kernel(
    const float* __restrict__ x, const float* __restrict__ b2,
    const float* __restrict__ ws, const float* __restrict__ t,
    float* __restrict__ out) {
  __shared__ float xh[16 * 256];     // [ch][256] (196 used: 14x14 halo)
  int tid = threadIdx.x;
  int tile = blockIdx.x, g = blockIdx.y, b = blockIdx.z;
  int ty = (tile >> 3) * 8, tx = (tile & 7) * 8;
  int py = tid >> 3, px = tid & 7;

  // issue t-tile loads into registers (lane = pixel, contiguous 64 floats)
  const float4* __restrict__ tt =
      (const float4*)(t + ((size_t)(b * 64 + tile) * 64 + tid) * 64);
  float4 tr[16];
#pragma unroll
  for (int i = 0; i < 16; ++i) tr[i] = tt[i];

  // halo slot geometry (4 slots of 64 per channel; slot i = r*14+cl)
  const float* __restrict__ zsrc = ws + ZERO_OFF;
  const float* __restrict__ xg = x + ((size_t)b * C + g * GC) * (H * W);
  int hofs[4];
  bool hval[4];
#pragma unroll
  for (int ii = 0; ii < 4; ++ii) {
    int i = ii * 64 + tid;
    int r = i / 14, cl = i - r * 14;
    int gy = ty - PADD + r, gx = tx - PADD + cl;
    bool v = (i < 196) && ((unsigned)gy < H) && ((unsigned)gx < W);
    hval[ii] = v;
    hofs[ii] = gy * W + gx;
  }

  // issue halo loads for channels 0..7 (32 vmem ops in flight)
#pragma unroll
  for (int ch = 0; ch < 8; ++ch) {
    const float* xc = xg + ch * (H * W);
#pragma unroll
    for (int ii = 0; ii < 4; ++ii) {
      const float* s = hval[ii] ? (xc + hofs[ii]) : zsrc;
      gload_lds4(s, &xh[ch * 256 + ii * 64]);
    }
  }

  // wgt GEMM: wgt[k] = b2[g*49+k] + sum_o w2T[o][g*49+k] * t[o][pix]
  float wgt[K2];
  const float* __restrict__ b2g = b2 + g * K2;
#pragma unroll
  for (int k = 0; k < K2; ++k) wgt[k] = b2g[k];
  const float* __restrict__ w2Tg = ws + W2T_OFF + g * K2;
#pragma unroll
  for (int i = 0; i < 16; ++i) {
#pragma unroll
    for (int j = 0; j < 4; ++j) {
      float tv = (&tr[i].x)[j];
      const float* __restrict__ wr = w2Tg + (i * 4 + j) * 784;
#pragma unroll
      for (int k = 0; k < K2; ++k) wgt[k] = fmaf(wr[k], tv, wgt[k]);
    }
  }

  // keep outstanding vmem <= 48 before issuing the second halo batch
  asm volatile("s_waitcnt vmcnt(16)" ::: "memory");
#pragma unroll
  for (int ch = 8; ch < 16; ++ch) {
    const float* xc = xg + ch * (H * W);
#pragma unroll
    for (int ii = 0; ii < 4; ++ii) {
      const float* s = hval[ii] ? (xc + hofs[ii]) : zsrc;
      gload_lds4(s, &xh[ch * 256 + ii * 64]);
    }
  }

  const float* __restrict__ s2 = ws + S2_OFF + g * GC;
  const float* __restrict__ b2c = ws + B2C_OFF + g * GC;
  float outv[16];

  // halo 0..7 complete when outstanding <= 32 (the just-issued batch)
  asm volatile("s_waitcnt vmcnt(32)" ::: "memory");
#pragma unroll
  for (int ch = 0; ch < 8; ++ch) {
    float acc = 0.f;
    int base = ch * 256 + py * 14 + px;
#pragma unroll
    for (int di = 0; di < KS; ++di)
#pragma unroll
      for (int dj = 0; dj < KS; ++dj)
        acc = fmaf(xh[base + di * 14 + dj], wgt[di * KS + dj], acc);
    outv[ch] = fmaxf(fmaf(acc, s2[ch], b2c[ch]), 0.f);
  }

  asm volatile("s_waitcnt vmcnt(0)" ::: "memory");
#pragma unroll
  for (int ch = 8; ch < 16; ++ch) {
    float acc = 0.f;
    int base = ch * 256 + py * 14 + px;
#pragma unroll
    for (int di = 0; di < KS; ++di)
#pragma unroll
      for (int dj = 0; dj < KS; ++dj)
        acc = fmaf(xh[base + di * 14 + dj], wgt[di * KS + dj], acc);
    outv[ch] = fmaxf(fmaf(acc, s2[ch], b2c[ch]), 0.f);
  }

#pragma unroll
  for (int ch = 0; ch < 16; ++ch)
    out[(((size_t)b * C + g * GC + ch) * H + ty + py) * W + tx + px] = outv[ch];
}

extern "C" void kernel_launch(void* const* d_in, const int* in_sizes, int n_in,
                              void* d_out, int out_size, void* d_ws, size_t ws_size,
                              hipStream_t stream) {
  const float* x   = (const float*)d_in[0];
  const float* w1  = (const float*)d_in[1];
  const float* g1  = (const float*)d_in[2];
  const float* be1 = (const float*)d_in[3];
  const float* m1  = (const float*)d_in[4];
  const float* v1  = (const float*)d_in[5];
  const float* w2  = (const float*)d_in[6];
  const float* b2  = (const float*)d_in[7];
  const float* g2  = (const float*)d_in[8];
  const float* be2 = (const float*)d_in[9];
  const float* m2  = (const float*)d_in[10];
  const float* v2  = (const float*)d_in[11];
  float* outp = (float*)d_out;
  float* ws = (float*)d_ws;

  prep_kernel<<<dim3(64), dim3(256), 0, stream>>>(w1, w2, g1, be1, m1, v1,
                                                  g2, be2, m2, v2, ws);
  t_kernel<<<dim3(H, BN, 2), dim3(256), 0, stream>>>(x, ws, ws + T_OFF);
  inv_kernel<<<dim3(64, G, BN), dim3(64), 0, stream>>>(x, b2, ws, ws + T_OFF, outp);
}